// Round 4
// baseline (548.336 us; speedup 1.0000x reference)
//
#include <hip/hip_runtime.h>

// out[token, e] = W[e, idx[token]] + b[e]
//
// Pipeline (ws-gated):
//  K1 transpose+bias: Wt[v][e] = W[e][v] + b[e]   (IEEE-identical add; W read NT)
//  K2 histogram: count tokens per vocab-chunk (chunk = 2048 rows = 1 MB of Wt)
//  K3 prefix:   exclusive scan -> bucket bases; init cursors
//  K4 scatter:  exact-packed records {tok, row} per chunk (block-aggregated atomics)
//  K5 gather:   XCD-affine (blockIdx%8) per-chunk processing -> Wt reads L2-resident;
//               NT 512 B row stores to out (scattered but granule-contiguous).
//
// Theory under test: gather was read-side bound (random 512 B rows from L3/HBM,
// ~2.6 TB/s effective). Chunk+affinity makes reads L2-hits; writes stay NT.

#define EMB 128
#define CH_LOG 11               // 2048 vocab rows per chunk
#define MAXCHUNK 64             // >= ceil(100000/2048)=49; fixed array size

typedef float fx4 __attribute__((ext_vector_type(4)));

// ---- K1: tiled transpose + bias; block 0 zeroes chunk counters ------------
__global__ void transpose_bias_kernel(const float* __restrict__ W,
                                      const float* __restrict__ bias,
                                      float* __restrict__ Wt,
                                      int* __restrict__ counts, int V) {
    __shared__ float lds[64 * 129];
    const int v0 = blockIdx.x * 64;
    const int t  = threadIdx.x;

    if (blockIdx.x == 0 && t < MAXCHUNK) counts[t] = 0;

    #pragma unroll 8
    for (int j = t; j < 128 * 64; j += 256) {
        const int e    = j >> 6;
        const int vloc = j & 63;
        const int v    = v0 + vloc;
        float val = 0.0f;
        if (v < V) val = __builtin_nontemporal_load(&W[(size_t)e * V + v]);
        lds[vloc * 129 + e] = val;
    }
    __syncthreads();

    #pragma unroll 8
    for (int j = t; j < 64 * 128; j += 256) {
        const int vloc = j >> 7;
        const int e    = j & 127;
        const int v    = v0 + vloc;
        if (v < V) Wt[(size_t)v * EMB + e] = lds[vloc * 129 + e] + bias[e];
    }
}

// ---- K2: per-chunk histogram (LDS-aggregated) -----------------------------
__global__ __launch_bounds__(256) void hist_kernel(const int* __restrict__ idx,
                                                   int ntok,
                                                   int* __restrict__ counts) {
    __shared__ int lc[MAXCHUNK];
    const int t = threadIdx.x;
    if (t < MAXCHUNK) lc[t] = 0;
    __syncthreads();

    const int stride = gridDim.x * blockDim.x;
    for (int i = blockIdx.x * blockDim.x + t; i < ntok; i += stride)
        atomicAdd(&lc[idx[i] >> CH_LOG], 1);

    __syncthreads();
    if (t < MAXCHUNK && lc[t]) atomicAdd(&counts[t], lc[t]);
}

// ---- K3: exclusive prefix over MAXCHUNK counts; cursors = bases -----------
__global__ void prefix_kernel(int* __restrict__ counts,   // in: counts, out: cursors
                              int* __restrict__ base) {   // out: base[MAXCHUNK+1]
    if (threadIdx.x == 0 && blockIdx.x == 0) {
        int run = 0;
        for (int c = 0; c < MAXCHUNK; ++c) {
            base[c] = run;
            run += counts[c];
            counts[c] = base[c];           // counts[] becomes gcursor[]
        }
        base[MAXCHUNK] = run;
    }
}

// ---- K4: exact-packed scatter of {tok, row} records -----------------------
__global__ __launch_bounds__(256) void scatter_kernel(const int* __restrict__ idx,
                                                      int ntok,
                                                      int* __restrict__ gcur,
                                                      int2* __restrict__ rec) {
    __shared__ int lc[MAXCHUNK];
    __shared__ int lb[MAXCHUNK];
    const int t = threadIdx.x;
    if (t < MAXCHUNK) lc[t] = 0;
    __syncthreads();

    // two tokens per thread, coalesced
    const int j0 = blockIdx.x * 512 + t;
    int row0 = 0, row1 = 0, c0 = -1, c1 = -1, s0 = 0, s1 = 0;
    if (j0 < ntok)       { row0 = idx[j0];       c0 = row0 >> CH_LOG; }
    if (j0 + 256 < ntok) { row1 = idx[j0 + 256]; c1 = row1 >> CH_LOG; }
    if (c0 >= 0) s0 = atomicAdd(&lc[c0], 1);
    if (c1 >= 0) s1 = atomicAdd(&lc[c1], 1);
    __syncthreads();

    if (t < MAXCHUNK) lb[t] = lc[t] ? atomicAdd(&gcur[t], lc[t]) : 0;
    __syncthreads();

    if (c0 >= 0) rec[lb[c0] + s0] = make_int2(j0, row0);
    if (c1 >= 0) rec[lb[c1] + s1] = make_int2(j0 + 256, row1);
}

// ---- K5: XCD-affine bucketed gather ---------------------------------------
// blockIdx%8 -> presumed XCD; chunk c processed only by blocks with bid%8==c%8,
// so each XCD's L2 (4 MiB) holds the live 1 MB chunk of Wt.
__global__ __launch_bounds__(256) void gather_bucketed(
        const int2* __restrict__ rec, const int* __restrict__ base,
        const float* __restrict__ Wt, float* __restrict__ out) {
    const int t  = threadIdx.x;
    const int q  = t & 31;
    const int g  = t >> 5;                 // 0..7
    const int x  = blockIdx.x & 7;         // XCD class
    const int bi = blockIdx.x >> 3;        // block index within class
    const int nb = gridDim.x >> 3;         // blocks per class

    for (int c = x; c < MAXCHUNK; c += 8) {
        const int s = base[c];
        const int n = base[c + 1] - s;
        for (int i0 = bi * 64; i0 < n; i0 += nb * 64) {
            int2 r[8];
            #pragma unroll
            for (int p = 0; p < 8; ++p) {
                const int i = i0 + g + (p << 3);
                r[p] = (i < n) ? rec[s + i] : make_int2(-1, 0);
            }
            fx4 v[8];
            #pragma unroll
            for (int p = 0; p < 8; ++p)
                v[p] = ((const fx4*)(Wt + ((size_t)r[p].y << 7)))[q];
            #pragma unroll
            for (int p = 0; p < 8; ++p)
                if (r[p].x >= 0)
                    __builtin_nontemporal_store(
                        v[p], (fx4*)(out + ((size_t)r[p].x << 7)) + q);
        }
    }
}

// ---- mid-gate path: deep-ILP linear gather (Round-3 kernel) ---------------
__global__ __launch_bounds__(256) void gather_rows_deep(
        const int* __restrict__ idx, const float* __restrict__ Wt,
        float* __restrict__ out, int ntok) {
    const int t = threadIdx.x;
    const int q = t & 31;
    const int g = t >> 5;
    const int niter  = (ntok + 127) >> 7;
    const int stride = gridDim.x;

    for (int it = blockIdx.x; it < niter; it += stride) {
        const int tok0 = it << 7;
        int rows[16];
        #pragma unroll
        for (int p = 0; p < 16; ++p) {
            const int tok = tok0 + g + (p << 3);
            rows[p] = (tok < ntok) ? idx[tok] : 0;
        }
        fx4 v[16];
        #pragma unroll
        for (int p = 0; p < 16; ++p)
            v[p] = ((const fx4*)(Wt + ((size_t)rows[p] << 7)))[q];
        #pragma unroll
        for (int p = 0; p < 16; ++p) {
            const int tok = tok0 + g + (p << 3);
            if (tok < ntok)
                __builtin_nontemporal_store(
                    v[p], (fx4*)(out + ((size_t)tok << 7)) + q);
        }
    }
}

// ---- fallback: direct gather ----------------------------------------------
__global__ void gather_direct_kernel(const int* __restrict__ idx,
                                     const float* __restrict__ W,
                                     const float* __restrict__ bias,
                                     float* __restrict__ out, int ntok, int V) {
    const long long total  = (long long)ntok * EMB;
    const long long stride = (long long)gridDim.x * blockDim.x;
    for (long long i = (long long)blockIdx.x * blockDim.x + threadIdx.x;
         i < total; i += stride) {
        const int token = (int)(i >> 7);
        const int e     = (int)(i & (EMB - 1));
        out[i] = W[(size_t)e * V + idx[token]] + bias[e];
    }
}

extern "C" void kernel_launch(void* const* d_in, const int* in_sizes, int n_in,
                              void* d_out, int out_size, void* d_ws, size_t ws_size,
                              hipStream_t stream) {
    const int*   x = (const int*)d_in[0];
    const float* W = (const float*)d_in[1];
    const float* b = (const float*)d_in[2];
    float* out = (float*)d_out;

    const int ntok = in_sizes[0];           // 819200
    const int V    = in_sizes[1] / EMB;     // 100000

    // ws layout
    const size_t wt_bytes = (size_t)V * EMB * sizeof(float);         // 51.2 MB
    const size_t offA = (wt_bytes + 511) & ~(size_t)511;             // cursors (256 B)
    const size_t offB = offA + 512;                                  // base (260 B)
    const size_t offC = offB + 512;                                  // records
    const size_t need_bucketed = offC + (size_t)ntok * sizeof(int2); // ~58 MB

    if (ws_size >= need_bucketed && V <= (MAXCHUNK << CH_LOG)) {
        float* Wt   = (float*)d_ws;
        int*   cur  = (int*)((char*)d_ws + offA);
        int*   base = (int*)((char*)d_ws + offB);
        int2*  rec  = (int2*)((char*)d_ws + offC);

        const int tblocks = (V + 63) / 64;
        transpose_bias_kernel<<<tblocks, 256, 0, stream>>>(W, b, Wt, cur, V);
        hist_kernel<<<1280, 256, 0, stream>>>(x, ntok, cur);
        prefix_kernel<<<1, 64, 0, stream>>>(cur, base);
        scatter_kernel<<<(ntok + 511) / 512, 256, 0, stream>>>(x, ntok, cur, rec);
        gather_bucketed<<<1280, 256, 0, stream>>>(rec, base, Wt, out);
    } else if (ws_size >= wt_bytes) {
        float* Wt = (float*)d_ws;
        const int tblocks = (V + 63) / 64;
        transpose_bias_kernel<<<tblocks, 256, 0, stream>>>(W, b, Wt, (int*)nullptr, V);
        gather_rows_deep<<<1280, 256, 0, stream>>>(x, Wt, out, ntok);
    } else {
        gather_direct_kernel<<<2048, 256, 0, stream>>>(x, W, b, out, ntok, V);
    }
}